// Round 1
// baseline (380.191 us; speedup 1.0000x reference)
//
#include <hip/hip_runtime.h>
#include <math.h>

#define EPS 1e-5f

constexpr int Mc = 8192;   // memory rows per batch
constexpr int Wc = 32;     // word size
constexpr int Hc = 4;      // heads
constexpr int NT = 1024;   // threads per block (16 waves)
constexpr int LD = Mc + 8; // padded LDS row stride (8200 % 32 == 8 -> conflict-free phase-1 writes)

__global__ __launch_bounds__(NT, 4) void weightfn_kernel(
    const float* __restrict__ memory,
    const float* __restrict__ keys,
    const float* __restrict__ strengths,
    float* __restrict__ out)
{
    // ~131 KB sharp buffer + small scratch; 1 block/CU by design (160 KB LDS on gfx950)
    __shared__ __align__(16) float s_sharp[Hc * LD];
    __shared__ __align__(16) float s_key[Hc * Wc];
    __shared__ float s_kn[Hc];    // key norms
    __shared__ float s_beta[Hc];  // softplus(strengths)
    __shared__ float s_redm[NT / 64][Hc];
    __shared__ float s_redl[NT / 64][Hc];
    __shared__ float s_max[Hc];
    __shared__ float s_inv[Hc];

    const int b = blockIdx.x;
    const int t = threadIdx.x;

    // ---- load keys, compute key norms and softplus(strengths) ----
    if (t < Hc * Wc) s_key[t] = keys[(size_t)b * Hc * Wc + t];
    __syncthreads();
    if (t < Hc) {
        float s = 0.f;
        #pragma unroll
        for (int w = 0; w < Wc; ++w) { float k = s_key[t * Wc + w]; s += k * k; }
        s_kn[t] = sqrtf(s + EPS);
        float x = strengths[(size_t)b * Hc + t];
        // numerically stable softplus, matches np/jax closely
        s_beta[t] = fmaxf(x, 0.f) + log1pf(expf(-fabsf(x)));
    }
    __syncthreads();

    // ---- phase 1: stream memory[b], compute sharp[h][m] into LDS ----
    const int w4 = t & 7;   // which float4 of the 32-float row
    const int mg = t >> 3;  // row group base
    const float4* mp = reinterpret_cast<const float4*>(memory) + (size_t)b * (Mc * Wc / 4);
    const float4* kp = reinterpret_cast<const float4*>(s_key);
    const float4 k0 = kp[0 * 8 + w4];
    const float4 k1 = kp[1 * 8 + w4];
    const float4 k2 = kp[2 * 8 + w4];
    const float4 k3 = kp[3 * 8 + w4];
    const float myKn   = s_kn[w4 & 3];
    const float myBeta = s_beta[w4 & 3];

    #pragma unroll 4
    for (int k = 0; k < Mc / (NT / 8); ++k) {   // 64 iterations, 128 rows each
        const int m = mg + k * (NT / 8);
        float4 v = mp[t + k * NT];              // fully coalesced: flat index t + k*1024
        float sq = v.x * v.x + v.y * v.y + v.z * v.z + v.w * v.w;
        float d0 = v.x * k0.x + v.y * k0.y + v.z * k0.z + v.w * k0.w;
        float d1 = v.x * k1.x + v.y * k1.y + v.z * k1.z + v.w * k1.w;
        float d2 = v.x * k2.x + v.y * k2.y + v.z * k2.z + v.w * k2.w;
        float d3 = v.x * k3.x + v.y * k3.y + v.z * k3.z + v.w * k3.w;
        // reduce across the 8 lanes that share this row
        #pragma unroll
        for (int off = 1; off <= 4; off <<= 1) {
            sq += __shfl_xor(sq, off);
            d0 += __shfl_xor(d0, off);
            d1 += __shfl_xor(d1, off);
            d2 += __shfl_xor(d2, off);
            d3 += __shfl_xor(d3, off);
        }
        if (w4 < Hc) {
            float d = (w4 == 0) ? d0 : (w4 == 1) ? d1 : (w4 == 2) ? d2 : d3;
            float mn = sqrtf(sq + EPS);
            s_sharp[w4 * LD + m] = d * myBeta / (myKn * mn + EPS);
        }
    }
    __syncthreads();

    // ---- phase 2a: block-wide max per head ----
    const int wave = t >> 6;
    const int lane = t & 63;
    float mx[Hc];
    #pragma unroll
    for (int h = 0; h < Hc; ++h) mx[h] = -INFINITY;
    #pragma unroll
    for (int k = 0; k < Mc / NT; ++k) {
        const int m = t + k * NT;
        #pragma unroll
        for (int h = 0; h < Hc; ++h) mx[h] = fmaxf(mx[h], s_sharp[h * LD + m]);
    }
    #pragma unroll
    for (int off = 1; off < 64; off <<= 1) {
        #pragma unroll
        for (int h = 0; h < Hc; ++h) mx[h] = fmaxf(mx[h], __shfl_xor(mx[h], off));
    }
    if (lane == 0) {
        #pragma unroll
        for (int h = 0; h < Hc; ++h) s_redm[wave][h] = mx[h];
    }
    __syncthreads();
    if (t < Hc) {
        float m0 = s_redm[0][t];
        #pragma unroll
        for (int i = 1; i < NT / 64; ++i) m0 = fmaxf(m0, s_redm[i][t]);
        s_max[t] = m0;
    }
    __syncthreads();

    // ---- phase 2b: block-wide sum of exp per head ----
    float gm[Hc];
    #pragma unroll
    for (int h = 0; h < Hc; ++h) gm[h] = s_max[h];
    float ls[Hc];
    #pragma unroll
    for (int h = 0; h < Hc; ++h) ls[h] = 0.f;
    #pragma unroll
    for (int k = 0; k < Mc / NT; ++k) {
        const int m = t + k * NT;
        #pragma unroll
        for (int h = 0; h < Hc; ++h) ls[h] += expf(s_sharp[h * LD + m] - gm[h]);
    }
    #pragma unroll
    for (int off = 1; off < 64; off <<= 1) {
        #pragma unroll
        for (int h = 0; h < Hc; ++h) ls[h] += __shfl_xor(ls[h], off);
    }
    if (lane == 0) {
        #pragma unroll
        for (int h = 0; h < Hc; ++h) s_redl[wave][h] = ls[h];
    }
    __syncthreads();
    if (t < Hc) {
        float s = 0.f;
        #pragma unroll
        for (int i = 0; i < NT / 64; ++i) s += s_redl[i][t];
        s_inv[t] = 1.f / s;   // s >= 1 always (contains exp(0))
    }
    __syncthreads();

    // ---- phase 3: normalized softmax output, coalesced float4 stores ----
    float4* op = reinterpret_cast<float4*>(out) + (size_t)b * (Hc * Mc / 4);
    #pragma unroll
    for (int k = 0; k < (Hc * Mc / 4) / NT; ++k) {   // 8 iterations
        const int f = t + k * NT;
        const int h = f >> 11;        // / (Mc/4)
        const int r = f & 2047;       // float4 index within the head row
        float4 v = *reinterpret_cast<const float4*>(&s_sharp[h * LD + r * 4]);
        const float gmh = s_max[h];
        const float gih = s_inv[h];
        float4 o;
        o.x = expf(v.x - gmh) * gih;
        o.y = expf(v.y - gmh) * gih;
        o.z = expf(v.z - gmh) * gih;
        o.w = expf(v.w - gmh) * gih;
        op[f] = o;
    }
}

extern "C" void kernel_launch(void* const* d_in, const int* in_sizes, int n_in,
                              void* d_out, int out_size, void* d_ws, size_t ws_size,
                              hipStream_t stream) {
    const float* memory    = (const float*)d_in[0];
    const float* keys      = (const float*)d_in[1];
    const float* strengths = (const float*)d_in[2];
    float* out = (float*)d_out;

    const int B = in_sizes[0] / (Mc * Wc);   // 256
    dim3 grid(B), block(NT);
    hipLaunchKernelGGL(weightfn_kernel, grid, block, 0, stream,
                       memory, keys, strengths, out);
}

// Round 2
// 376.749 us; speedup vs baseline: 1.0091x; 1.0091x over previous
//
#include <hip/hip_runtime.h>
#include <math.h>

#define EPS 1e-5f

constexpr int Mc = 8192;   // memory rows per batch
constexpr int Wc = 32;     // word size
constexpr int Hc = 4;      // heads
constexpr int NT = 1024;   // threads per block (16 waves)
constexpr int LD = Mc + 8; // padded LDS row stride: (8h + m) -> conflict-free phase-1 writes

__global__ __launch_bounds__(NT, 4) void weightfn_kernel(
    const float* __restrict__ memory,
    const float* __restrict__ keys,
    const float* __restrict__ strengths,
    float* __restrict__ out)
{
    // ~131 KB exp(sharp) buffer; 1 block/CU by design (160 KB LDS on gfx950)
    __shared__ __align__(16) float s_sharp[Hc * LD];   // holds exp(sharp) after phase 1
    __shared__ __align__(16) float s_key[Hc * Wc];
    __shared__ float s_kn[Hc];              // key norms
    __shared__ float s_beta[Hc];            // softplus(strengths)
    __shared__ float s_redl[NT / 64][Hc];   // per-wave partial exp-sums
    __shared__ float s_inv[Hc];             // 1 / softmax denominator

    const int b = blockIdx.x;
    const int t = threadIdx.x;

    // ---- load keys, compute key norms and softplus(strengths) ----
    if (t < Hc * Wc) s_key[t] = keys[(size_t)b * Hc * Wc + t];
    __syncthreads();
    if (t < Hc) {
        float s = 0.f;
        #pragma unroll
        for (int w = 0; w < Wc; ++w) { float k = s_key[t * Wc + w]; s += k * k; }
        s_kn[t] = sqrtf(s + EPS);
        float x = strengths[(size_t)b * Hc + t];
        // numerically stable softplus (fp64-free, matches np within fp32 rounding)
        s_beta[t] = fmaxf(x, 0.f) + log1pf(expf(-fabsf(x)));
    }
    __syncthreads();

    // ---- phase 1: stream memory[b]; exp(sharp) -> LDS; online denominator ----
    // lane layout: 8 lanes per row, lane w4 owns float4 chunk w4 of the row.
    const int w4 = t & 7;
    const int mg = t >> 3;
    const float4* mp = reinterpret_cast<const float4*>(memory) + (size_t)b * (Mc * Wc / 4);
    const float4* kp = reinterpret_cast<const float4*>(s_key);
    const float4 k0 = kp[0 * 8 + w4];
    const float4 k1 = kp[1 * 8 + w4];
    const float4 k2 = kp[2 * 8 + w4];
    const float4 k3 = kp[3 * 8 + w4];
    const float myKn   = s_kn[w4 & 3];
    const float myBeta = s_beta[w4 & 3];

    float esum = 0.f;   // this lane's partial softmax denominator (head = w4, if w4 < 4)

    #pragma unroll 4
    for (int k = 0; k < Mc / (NT / 8); ++k) {   // 64 iterations, 128 rows each
        const int m = mg + k * (NT / 8);
        float4 v = mp[t + k * NT];              // fully coalesced: flat index t + k*1024
        float sq = v.x * v.x + v.y * v.y + v.z * v.z + v.w * v.w;
        float d0 = v.x * k0.x + v.y * k0.y + v.z * k0.z + v.w * k0.w;
        float d1 = v.x * k1.x + v.y * k1.y + v.z * k1.z + v.w * k1.w;
        float d2 = v.x * k2.x + v.y * k2.y + v.z * k2.z + v.w * k2.w;
        float d3 = v.x * k3.x + v.y * k3.y + v.z * k3.z + v.w * k3.w;
        // reduce across the 8 lanes sharing this row (DPP-lowered xor adds)
        #pragma unroll
        for (int off = 1; off <= 4; off <<= 1) {
            sq += __shfl_xor(sq, off);
            d0 += __shfl_xor(d0, off);
            d1 += __shfl_xor(d1, off);
            d2 += __shfl_xor(d2, off);
            d3 += __shfl_xor(d3, off);
        }
        if (w4 < Hc) {
            float d = (w4 == 0) ? d0 : (w4 == 1) ? d1 : (w4 == 2) ? d2 : d3;
            float mn = sqrtf(sq + EPS);
            // |sharp| <= softplus(max strength) ~ 3.5 -> exp() safe without max-sub
            float e = __expf(d * myBeta * __builtin_amdgcn_rcpf(myKn * mn + EPS));
            s_sharp[w4 * LD + m] = e;
            esum += e;
        }
    }

    // ---- phase 2: block reduction of the per-head denominators ----
    const int wave = t >> 6;
    // xor 8/16/32 preserves lane&7, so head lanes (w4<4) combine with same-head lanes
    #pragma unroll
    for (int off = 8; off <= 32; off <<= 1) esum += __shfl_xor(esum, off);
    if ((t & 63) < Hc) s_redl[wave][w4] = esum;   // lanes 0..3 of each wave
    __syncthreads();
    if (t < Hc) {
        float s = 0.f;
        #pragma unroll
        for (int i = 0; i < NT / 64; ++i) s += s_redl[i][t];
        s_inv[t] = __builtin_amdgcn_rcpf(s);   // s >= 8192*exp(-3.5) > 0, well-scaled
    }
    __syncthreads();

    // ---- phase 3: scale & store, coalesced float4 ----
    float4* op = reinterpret_cast<float4*>(out) + (size_t)b * (Hc * Mc / 4);
    #pragma unroll
    for (int k = 0; k < (Hc * Mc / 4) / NT; ++k) {   // 8 iterations
        const int f = t + k * NT;
        const int h = f >> 11;        // / (Mc/4)
        const int r = f & 2047;       // float4 index within the head row
        float4 v = *reinterpret_cast<const float4*>(&s_sharp[h * LD + r * 4]);
        const float gih = s_inv[h];
        float4 o;
        o.x = v.x * gih;
        o.y = v.y * gih;
        o.z = v.z * gih;
        o.w = v.w * gih;
        op[f] = o;
    }
}

extern "C" void kernel_launch(void* const* d_in, const int* in_sizes, int n_in,
                              void* d_out, int out_size, void* d_ws, size_t ws_size,
                              hipStream_t stream) {
    const float* memory    = (const float*)d_in[0];
    const float* keys      = (const float*)d_in[1];
    const float* strengths = (const float*)d_in[2];
    float* out = (float*)d_out;

    const int B = in_sizes[0] / (Mc * Wc);   // 256
    dim3 grid(B), block(NT);
    hipLaunchKernelGGL(weightfn_kernel, grid, block, 0, stream,
                       memory, keys, strengths, out);
}